// Round 5
// baseline (920.420 us; speedup 1.0000x reference)
//
#include <hip/hip_runtime.h>
#include <hip/hip_bf16.h>

#define B_ 16
#define S_ 80
#define D_ 512
#define H_ 64
#define DI_ 2048
#define L_ 6
#define G4H 256            // 4*H
#define NROW (B_ * S_)     // 1280 rows = (b, s)
#define EPS_ 1e-6f

typedef __attribute__((ext_vector_type(8))) short short8;
typedef __attribute__((ext_vector_type(4))) float f32x4;

// ---------------- math helpers ----------------
__device__ __forceinline__ float sigmoidf_(float x) {
    return __fdividef(1.0f, 1.0f + __expf(-x));
}
__device__ __forceinline__ float tanh_(float x) {
    return __fdividef(2.0f, 1.0f + __expf(-2.0f * x)) - 1.0f;
}
__device__ __forceinline__ short f2bf(float f) {
    __hip_bfloat16 h = __float2bfloat16(f);   // RNE
    return *reinterpret_cast<short*>(&h);
}

// Barrier that waits only on LDS traffic (lgkmcnt), NOT on in-flight global loads.
__device__ __forceinline__ void lds_barrier() {
    __asm__ volatile("s_waitcnt lgkmcnt(0)\n\ts_barrier" ::: "memory");
}

// ---------------- fp32 -> bf16 weight conversion (once per launch) ----------------
__global__ __launch_bounds__(256)
void w2bf_kernel(const float* __restrict__ s, __hip_bfloat16* __restrict__ d, int n4) {
    int i = blockIdx.x * 256 + threadIdx.x;
    if (i < n4) {
        float4 v = reinterpret_cast<const float4*>(s)[i];
        short4 o;
        o.x = f2bf(v.x); o.y = f2bf(v.y); o.z = f2bf(v.z); o.w = f2bf(v.w);
        reinterpret_cast<short4*>(d)[i] = o;
    }
}

// ---------------- Whh -> per-lane bf16 B-fragment layout for lstm_v9 ----------------
// wfb[l][((g*4+n)*2+kc)*512 + lane*8 + j] =
//     bf16( whh[l][g*64 + (lane&15)*4 + n][kc*32 + (lane>>4)*8 + j] )
// i.e. B[k][col=l16] for tile (g,n) with unit = 4*col + n (unit-interleaved columns).
__global__ __launch_bounds__(256)
void whh_frag9_kernel(const float* __restrict__ whh, __hip_bfloat16* __restrict__ wfb) {
    int idx = blockIdx.x * 256 + threadIdx.x;          // total L_*16384 = 98304
    int j    = idx & 7;
    int lane = (idx >> 3) & 63;
    int kc   = (idx >> 9) & 1;
    int n    = (idx >> 10) & 3;
    int g    = (idx >> 12) & 3;
    int l    = idx >> 14;
    int row = g * 64 + (lane & 15) * 4 + n;
    int col = kc * 32 + (lane >> 4) * 8 + j;
    wfb[idx] = __float2bfloat16(whh[((size_t)l * G4H + row) * H_ + col]);
}

// ---------------- LayerNorm: one block per row, shuffle reduce (2 barriers) ----------------
__global__ __launch_bounds__(256)
void ln_kernel(const float* __restrict__ x, const float* __restrict__ g,
               const float* __restrict__ b, __hip_bfloat16* __restrict__ out) {
    int row = blockIdx.x;
    int t = threadIdx.x;
    const float* xr = x + (size_t)row * D_;
    float v0 = xr[t], v1 = xr[t + 256];
    __shared__ float ws4[4], qs4[4];
    float s = v0 + v1;
    #pragma unroll
    for (int o = 32; o > 0; o >>= 1) s += __shfl_down(s, o);
    if ((t & 63) == 0) ws4[t >> 6] = s;
    __syncthreads();
    float m = (ws4[0] + ws4[1] + ws4[2] + ws4[3]) * (1.0f / (float)D_);
    float d0 = v0 - m, d1 = v1 - m;
    float q = d0 * d0 + d1 * d1;
    #pragma unroll
    for (int o = 32; o > 0; o >>= 1) q += __shfl_down(q, o);
    if ((t & 63) == 0) qs4[t >> 6] = q;
    __syncthreads();
    float rs = rsqrtf((qs4[0] + qs4[1] + qs4[2] + qs4[3]) * (1.0f / (float)D_) + EPS_);
    __hip_bfloat16* orow = out + (size_t)row * D_;
    orow[t]       = __float2bfloat16(d0 * rs * g[t]       + b[t]);
    orow[t + 256] = __float2bfloat16(d1 * rs * g[t + 256] + b[t + 256]);
}

// ---------------- bf16 MFMA GEMM: C[M,N] = A[M,K] @ W[N,K]^T (+bias)(+relu)(+res) -----------
// OUT_MODE: 0 = fp32 row-major, 1 = bf16 row-major,
//           2 = fp32 xg6 layout [s][b][u>>2][u&3][g]  (per-lane-contiguous for lstm_v9)
template<int WITH_BIAS, int WITH_RELU, int WITH_RES, int OUT_MODE>
__global__ __launch_bounds__(256)
void mfma_gemm(const __hip_bfloat16* __restrict__ A, const __hip_bfloat16* __restrict__ W,
               const float* __restrict__ bias, const float* __restrict__ res,
               void* __restrict__ C, int M, int N, int K) {
    const int LDT = 72;  // LDS row stride in shorts (144B rows, 16B-aligned)
    __shared__ short As[64 * LDT];
    __shared__ short Ws[64 * LDT];

    int tid  = threadIdx.x;
    int wave = tid >> 6, lane = tid & 63;
    int quad = lane >> 4, l16 = lane & 15;
    int m_off = (wave >> 1) * 32, n_off = (wave & 1) * 32;
    int m0 = blockIdx.y * 64, n0 = blockIdx.x * 64;

    int r = tid >> 2, c = tid & 3;           // staging: row 0..63, 16-elem chunk 0..3
    const short* Ag = reinterpret_cast<const short*>(A);
    const short* Wg = reinterpret_cast<const short*>(W);

    f32x4 acc00 = {0.f,0.f,0.f,0.f}, acc01 = acc00, acc10 = acc00, acc11 = acc00;

    short8 avA[2], avW[2];                   // staged tile in registers
    auto load_tile = [&](int k0) {
        const short* arow = &Ag[(size_t)(m0 + r) * K + k0 + c * 16];
        avA[0] = *reinterpret_cast<const short8*>(arow);
        avA[1] = *reinterpret_cast<const short8*>(arow + 8);
        const short* wrow = &Wg[(size_t)(n0 + r) * K + k0 + c * 16];
        avW[0] = *reinterpret_cast<const short8*>(wrow);
        avW[1] = *reinterpret_cast<const short8*>(wrow + 8);
    };

    load_tile(0);                            // prologue
    for (int k0 = 0; k0 < K; k0 += 64) {
        lds_barrier();                       // prev frag reads done; vmem stays in flight
        *reinterpret_cast<short8*>(&As[r * LDT + c * 16])     = avA[0];
        *reinterpret_cast<short8*>(&As[r * LDT + c * 16 + 8]) = avA[1];
        *reinterpret_cast<short8*>(&Ws[r * LDT + c * 16])     = avW[0];
        *reinterpret_cast<short8*>(&Ws[r * LDT + c * 16 + 8]) = avW[1];
        lds_barrier();
        if (k0 + 64 < K) load_tile(k0 + 64); // issue next loads; consumed next iteration

        #pragma unroll
        for (int kc = 0; kc < 2; kc++) {
            short8 a0 = *reinterpret_cast<const short8*>(&As[(m_off + l16) * LDT + kc * 32 + quad * 8]);
            short8 a1 = *reinterpret_cast<const short8*>(&As[(m_off + 16 + l16) * LDT + kc * 32 + quad * 8]);
            short8 b0 = *reinterpret_cast<const short8*>(&Ws[(n_off + l16) * LDT + kc * 32 + quad * 8]);
            short8 b1 = *reinterpret_cast<const short8*>(&Ws[(n_off + 16 + l16) * LDT + kc * 32 + quad * 8]);
            acc00 = __builtin_amdgcn_mfma_f32_16x16x32_bf16(a0, b0, acc00, 0, 0, 0);
            acc01 = __builtin_amdgcn_mfma_f32_16x16x32_bf16(a0, b1, acc01, 0, 0, 0);
            acc10 = __builtin_amdgcn_mfma_f32_16x16x32_bf16(a1, b0, acc10, 0, 0, 0);
            acc11 = __builtin_amdgcn_mfma_f32_16x16x32_bf16(a1, b1, acc11, 0, 0, 0);
        }
    }

    f32x4 accs[2][2] = {{acc00, acc01}, {acc10, acc11}};
    #pragma unroll
    for (int fi = 0; fi < 2; fi++) {
        #pragma unroll
        for (int fj = 0; fj < 2; fj++) {
            int coln = n0 + n_off + fj * 16 + l16;
            float bv = WITH_BIAS ? bias[coln] : 0.0f;
            #pragma unroll
            for (int rr = 0; rr < 4; rr++) {
                int rowm = m0 + m_off + fi * 16 + quad * 4 + rr;
                float v = accs[fi][fj][rr];
                if (WITH_BIAS) v += bv;
                if (WITH_RELU) v = fmaxf(v, 0.0f);
                if (WITH_RES)  v += res[(size_t)rowm * N + coln];
                if (OUT_MODE == 0) {
                    reinterpret_cast<float*>(C)[(size_t)rowm * N + coln] = v;
                } else if (OUT_MODE == 1) {
                    reinterpret_cast<__hip_bfloat16*>(C)[(size_t)rowm * N + coln] = __float2bfloat16(v);
                } else {
                    int b_ = rowm / S_;
                    int s_ = rowm - b_ * S_;
                    int g = coln >> 6, u = coln & 63;
                    reinterpret_cast<float*>(C)[
                        (size_t)s_ * 4096 + b_ * 256 + (u >> 2) * 16 + (u & 3) * 4 + g] = v;
                }
            }
        }
    }
}

// ---------------- MFMA LSTM v9: single-wave recurrences, bpermute h-exchange ----------------
// v4/v6/v8 established the step time is a FIXED serial chain dominated by the cross-wave
// h exchange (ds_write -> lgkmcnt -> s_barrier -> ds_read). v9 makes the recurrence
// single-wave: each wave owns 4 complete sequences (grid 80 x 4 batch-quads, 64-thread
// blocks). Whh is held entirely in registers as 32 bf16 B-frags (AGPR-backed,
// launch_bounds(64,1) -> 512-reg unified budget). Per step: 32 MFMAs over
// (4 gates x 4 unit-tiles), unit-interleaved D columns (unit = 4*l16 + n) so the next
// step's A-fragments are EXACTLY 8 ds_bpermute ops -- no LDS buffer, no s_barrier,
// no cross-wave wait anywhere in the 80-step loop.
__global__ __launch_bounds__(64, 1)
void lstm_v9_kernel(const float* __restrict__ xg6,           // [S][16][16][4][4] fp32
                    const __hip_bfloat16* __restrict__ wfb,  // layer slice, 16384 bf16
                    __hip_bfloat16* __restrict__ hlast) {    // [B, S, H]
    const int i    = blockIdx.x;          // output position 0..79
    const int bq4  = blockIdx.y;          // batch quad: batches 4*bq4 .. 4*bq4+3
    const int lane = threadIdx.x;         // 0..63
    const int quad = lane >> 4, l16 = lane & 15;
    const int bg   = bq4 * 4 + quad;      // global batch owned on producer/nonlin side

    // Whh B-fragments: whole 256x64 in registers (32 x short8)
    short8 wf[4][4][2];
    {
        const short* ws = reinterpret_cast<const short*>(wfb);
        #pragma unroll
        for (int g = 0; g < 4; g++)
            #pragma unroll
            for (int n = 0; n < 4; n++)
                #pragma unroll
                for (int kc = 0; kc < 2; kc++)
                    wf[g][n][kc] = *reinterpret_cast<const short8*>(
                        &ws[((((g * 4 + n) * 2 + kc) * 64) + lane) * 8]);
    }

    // bpermute source-lane byte addresses: src = (l16>>2)*16 + kc*8 + quad*2 + mm
    int sa00 = 4 * ((l16 >> 2) * 16 + 0 + quad * 2 + 0);
    int sa01 = 4 * ((l16 >> 2) * 16 + 0 + quad * 2 + 1);
    int sa10 = 4 * ((l16 >> 2) * 16 + 8 + quad * 2 + 0);
    int sa11 = 4 * ((l16 >> 2) * 16 + 8 + quad * 2 + 1);
    const int vmask = ((l16 & 3) == 0) ? -1 : 0;   // A rows 0,4,8,12 real; others 0

    const f32x4 zacc = {0.f, 0.f, 0.f, 0.f};
    float c0 = 0.f, c1 = 0.f, c2 = 0.f, c3 = 0.f;  // cell states (units 4*l16+n, batch quad)
    int dw0 = 0, dw1 = 0;                          // packed h: (h[n0],h[n1]) / (h[n2],h[n3])

    // xg base: s*4096 + bg*256 + l16*16 ; float4 at +4n holds gates ifgo of unit 4*l16+n
    auto xbase = [&](int t) -> const float* {
        int s = (t == i) ? (S_ - 1) : ((t == S_ - 1) ? i : t);   // janossy permutation
        return xg6 + (size_t)s * 4096 + bg * 256 + l16 * 16;
    };

    float4 xqA[4], xqB[4];
    {
        const float* xb = xbase(0);
        #pragma unroll
        for (int n = 0; n < 4; n++) xqA[n] = *reinterpret_cast<const float4*>(xb + n * 4);
    }
    {
        const float* xb = xbase(1);
        #pragma unroll
        for (int n = 0; n < 4; n++) xqB[n] = *reinterpret_cast<const float4*>(xb + n * 4);
    }

    auto step = [&](int t, float4 (&xc)[4]) {
        // ---- h exchange: 8 bpermutes build both A-fragments (no barrier, no LDS buf) ----
        int p00 = __builtin_amdgcn_ds_bpermute(sa00, dw0);
        int p01 = __builtin_amdgcn_ds_bpermute(sa00, dw1);
        int p02 = __builtin_amdgcn_ds_bpermute(sa01, dw0);
        int p03 = __builtin_amdgcn_ds_bpermute(sa01, dw1);
        int p10 = __builtin_amdgcn_ds_bpermute(sa10, dw0);
        int p11 = __builtin_amdgcn_ds_bpermute(sa10, dw1);
        int p12 = __builtin_amdgcn_ds_bpermute(sa11, dw0);
        int p13 = __builtin_amdgcn_ds_bpermute(sa11, dw1);
        int4 t0; t0.x = p00 & vmask; t0.y = p01 & vmask; t0.z = p02 & vmask; t0.w = p03 & vmask;
        int4 t1; t1.x = p10 & vmask; t1.y = p11 & vmask; t1.z = p12 & vmask; t1.w = p13 & vmask;
        short8 af0 = __builtin_bit_cast(short8, t0);
        short8 af1 = __builtin_bit_cast(short8, t1);

        // ---- 32 MFMAs: D[row=4b][col] = h[b] @ Whh^T for all 256 gate-units ----
        f32x4 acc[4][4];
        #pragma unroll
        for (int g = 0; g < 4; g++)
            #pragma unroll
            for (int n = 0; n < 4; n++)
                acc[g][n] = __builtin_amdgcn_mfma_f32_16x16x32_bf16(
                    af1, wf[g][n][1],
                    __builtin_amdgcn_mfma_f32_16x16x32_bf16(af0, wf[g][n][0], zacc, 0, 0, 0),
                    0, 0, 0);

        // ---- nonlinearity: 4 uniform states/lane (batch quad, units 4*l16+n) ----
        float h0, h1, h2, h3;
        {
            float gi = acc[0][0][0] + xc[0].x, gf = acc[1][0][0] + xc[0].y;
            float gg = acc[2][0][0] + xc[0].z, go = acc[3][0][0] + xc[0].w;
            float cc = sigmoidf_(gf) * c0 + sigmoidf_(gi) * tanh_(gg);
            c0 = cc; h0 = sigmoidf_(go) * tanh_(cc);
        }
        {
            float gi = acc[0][1][0] + xc[1].x, gf = acc[1][1][0] + xc[1].y;
            float gg = acc[2][1][0] + xc[1].z, go = acc[3][1][0] + xc[1].w;
            float cc = sigmoidf_(gf) * c1 + sigmoidf_(gi) * tanh_(gg);
            c1 = cc; h1 = sigmoidf_(go) * tanh_(cc);
        }
        {
            float gi = acc[0][2][0] + xc[2].x, gf = acc[1][2][0] + xc[2].y;
            float gg = acc[2][2][0] + xc[2].z, go = acc[3][2][0] + xc[2].w;
            float cc = sigmoidf_(gf) * c2 + sigmoidf_(gi) * tanh_(gg);
            c2 = cc; h2 = sigmoidf_(go) * tanh_(cc);
        }
        {
            float gi = acc[0][3][0] + xc[3].x, gf = acc[1][3][0] + xc[3].y;
            float gg = acc[2][3][0] + xc[3].z, go = acc[3][3][0] + xc[3].w;
            float cc = sigmoidf_(gf) * c3 + sigmoidf_(gi) * tanh_(gg);
            c3 = cc; h3 = sigmoidf_(go) * tanh_(cc);
        }

        // prefetch xg for t+2 into the slot just consumed (2-step in-flight window)
        if (t + 2 < S_) {
            const float* xb = xbase(t + 2);
            #pragma unroll
            for (int n = 0; n < 4; n++) xc[n] = *reinterpret_cast<const float4*>(xb + n * 4);
        }

        // pack h -> 2 dwords for next step's bpermute
        unsigned u0 = (unsigned short)f2bf(h0), u1 = (unsigned short)f2bf(h1);
        unsigned u2 = (unsigned short)f2bf(h2), u3 = (unsigned short)f2bf(h3);
        dw0 = (int)(u0 | (u1 << 16));
        dw1 = (int)(u2 | (u3 << 16));
    };

    for (int t = 0; t < S_; t += 2) { step(t, xqA); step(t + 1, xqB); }

    // final h: units 4*l16..4*l16+3 contiguous -> one 8B store
    int2 hv; hv.x = dw0; hv.y = dw1;
    *reinterpret_cast<int2*>(&hlast[((size_t)bg * S_ + i) * H_ + 4 * l16]) = hv;
}

// ---------------- final LN + projection to one logit per row ----------------
__global__ __launch_bounds__(256)
void final_kernel(const float* __restrict__ x, const float* __restrict__ g,
                  const float* __restrict__ b, const float* __restrict__ wprj,
                  float* __restrict__ out) {
    int row = blockIdx.x;
    int t = threadIdx.x;
    const float* xr = x + (size_t)row * D_;
    float v0 = xr[t], v1 = xr[t + 256];
    __shared__ float red[256];
    red[t] = v0 + v1;
    __syncthreads();
    for (int o = 128; o > 0; o >>= 1) { if (t < o) red[t] += red[t + o]; __syncthreads(); }
    float m = red[0] * (1.0f / (float)D_);
    __syncthreads();
    float d0 = v0 - m, d1 = v1 - m;
    red[t] = d0 * d0 + d1 * d1;
    __syncthreads();
    for (int o = 128; o > 0; o >>= 1) { if (t < o) red[t] += red[t + o]; __syncthreads(); }
    float rs = rsqrtf(red[0] * (1.0f / (float)D_) + EPS_);
    __syncthreads();
    float y0 = (d0 * rs * g[t] + b[t]) * wprj[t];
    float y1 = (d1 * rs * g[t + 256] + b[t + 256]) * wprj[t + 256];
    red[t] = y0 + y1;
    __syncthreads();
    for (int o = 128; o > 0; o >>= 1) { if (t < o) red[t] += red[t + o]; __syncthreads(); }
    if (t == 0) out[row] = red[0];
}

// ---------------- host ----------------
extern "C" void kernel_launch(void* const* d_in, const int* in_sizes, int n_in,
                              void* d_out, int out_size, void* d_ws, size_t ws_size,
                              hipStream_t stream) {
    const float* src   = (const float*)d_in[0];
    const float* ln1_g = (const float*)d_in[2];
    const float* ln1_b = (const float*)d_in[3];
    const float* wih   = (const float*)d_in[4];   // [L, 4H, D]
    const float* whh   = (const float*)d_in[5];   // [L, 4H, H]
    const float* wfc   = (const float*)d_in[6];   // [L, D, H]
    const float* ln2_g = (const float*)d_in[7];
    const float* ln2_b = (const float*)d_in[8];
    const float* w1    = (const float*)d_in[9];   // [L, DI, D]
    const float* b1    = (const float*)d_in[10];  // [L, DI]
    const float* w2    = (const float*)d_in[11];  // [L, D, DI]
    const float* b2    = (const float*)d_in[12];  // [L, D]
    const float* lnf_g = (const float*)d_in[13];
    const float* lnf_b = (const float*)d_in[14];
    const float* wprj  = (const float*)d_in[15];  // [1, D]
    float* out = (float*)d_out;

    char* ws = (char*)d_ws;
    float* xcur = (float*)ws;                       ws += (size_t)NROW * D_  * 4;  // fp32 residual stream
    __hip_bfloat16* lnb = (__hip_bfloat16*)ws;      ws += (size_t)NROW * D_  * 2;  // LN output (bf16 A-operand)
    float* xg6  = (float*)ws;                       ws += (size_t)S_ * 4096  * 4;  // gate proj fp32 [s][b][u>>2][u&3][g]
    __hip_bfloat16* hb  = (__hip_bfloat16*)ws;      ws += (size_t)NROW * H_  * 2;  // LSTM h (bf16 A-operand)
    __hip_bfloat16* f1  = (__hip_bfloat16*)ws;      ws += (size_t)NROW * DI_ * 2;  // FFN hidden (bf16 A-operand)
    __hip_bfloat16* wihb = (__hip_bfloat16*)ws;     ws += (size_t)L_ * G4H * D_ * 2;
    __hip_bfloat16* wfcb = (__hip_bfloat16*)ws;     ws += (size_t)L_ * D_ * H_ * 2;
    __hip_bfloat16* w1b  = (__hip_bfloat16*)ws;     ws += (size_t)L_ * DI_ * D_ * 2;
    __hip_bfloat16* w2b  = (__hip_bfloat16*)ws;     ws += (size_t)L_ * D_ * DI_ * 2;
    __hip_bfloat16* whf  = (__hip_bfloat16*)ws;     ws += (size_t)L_ * 16384 * 2;  // Whh B-frag bf16

    // one-time (per launch) weight conversions to bf16
    {
        int n4;
        n4 = L_ * G4H * D_ / 4;
        w2bf_kernel<<<(n4 + 255) / 256, 256, 0, stream>>>(wih, wihb, n4);
        n4 = L_ * D_ * H_ / 4;
        w2bf_kernel<<<(n4 + 255) / 256, 256, 0, stream>>>(wfc, wfcb, n4);
        n4 = L_ * DI_ * D_ / 4;
        w2bf_kernel<<<(n4 + 255) / 256, 256, 0, stream>>>(w1, w1b, n4);
        n4 = L_ * D_ * DI_ / 4;
        w2bf_kernel<<<(n4 + 255) / 256, 256, 0, stream>>>(w2, w2b, n4);
        whh_frag9_kernel<<<(L_ * 16384) / 256, 256, 0, stream>>>(whh, whf);
    }

    hipMemcpyAsync(xcur, src, (size_t)NROW * D_ * sizeof(float),
                   hipMemcpyDeviceToDevice, stream);

    for (int l = 0; l < L_; l++) {
        // --- janossy layer ---
        ln_kernel<<<NROW, 256, 0, stream>>>(xcur, ln1_g + (size_t)l * D_,
                                            ln1_b + (size_t)l * D_, lnb);
        mfma_gemm<0, 0, 0, 2><<<dim3(G4H / 64, NROW / 64), 256, 0, stream>>>(
            lnb, wihb + (size_t)l * G4H * D_, nullptr, nullptr, xg6, NROW, G4H, D_);
        lstm_v9_kernel<<<dim3(S_, 4), 64, 0, stream>>>(
            xg6, whf + (size_t)l * 16384, hb);
        mfma_gemm<0, 0, 1, 0><<<dim3(D_ / 64, NROW / 64), 256, 0, stream>>>(
            hb, wfcb + (size_t)l * D_ * H_, nullptr, xcur, xcur, NROW, D_, H_);
        // --- FFN ---
        ln_kernel<<<NROW, 256, 0, stream>>>(xcur, ln2_g + (size_t)l * D_,
                                            ln2_b + (size_t)l * D_, lnb);
        mfma_gemm<1, 1, 0, 1><<<dim3(DI_ / 64, NROW / 64), 256, 0, stream>>>(
            lnb, w1b + (size_t)l * DI_ * D_, b1 + (size_t)l * DI_, nullptr, f1, NROW, DI_, D_);
        mfma_gemm<1, 0, 1, 0><<<dim3(D_ / 64, NROW / 64), 256, 0, stream>>>(
            f1, w2b + (size_t)l * D_ * DI_, b2 + (size_t)l * D_, xcur, xcur, NROW, D_, DI_);
    }
    final_kernel<<<NROW, 256, 0, stream>>>(xcur, lnf_g, lnf_b, wprj, out);
}

// Round 6
// 710.727 us; speedup vs baseline: 1.2950x; 1.2950x over previous
//
#include <hip/hip_runtime.h>
#include <hip/hip_bf16.h>

#define B_ 16
#define S_ 80
#define D_ 512
#define H_ 64
#define DI_ 2048
#define L_ 6
#define G4H 256            // 4*H
#define NROW (B_ * S_)     // 1280 rows = (b, s)
#define EPS_ 1e-6f

typedef __attribute__((ext_vector_type(8))) short short8;
typedef __attribute__((ext_vector_type(4))) float f32x4;

// ---------------- math helpers ----------------
__device__ __forceinline__ float sigmoidf_(float x) {
    return __fdividef(1.0f, 1.0f + __expf(-x));
}
__device__ __forceinline__ float tanh_(float x) {
    return __fdividef(2.0f, 1.0f + __expf(-2.0f * x)) - 1.0f;
}
__device__ __forceinline__ short f2bf(float f) {
    __hip_bfloat16 h = __float2bfloat16(f);   // RNE
    return *reinterpret_cast<short*>(&h);
}

// Barrier that waits only on LDS traffic (lgkmcnt), NOT on in-flight global loads.
__device__ __forceinline__ void lds_barrier() {
    __asm__ volatile("s_waitcnt lgkmcnt(0)\n\ts_barrier" ::: "memory");
}

// ---------------- fp32 -> bf16 weight conversion (once per launch) ----------------
__global__ __launch_bounds__(256)
void w2bf_kernel(const float* __restrict__ s, __hip_bfloat16* __restrict__ d, int n4) {
    int i = blockIdx.x * 256 + threadIdx.x;
    if (i < n4) {
        float4 v = reinterpret_cast<const float4*>(s)[i];
        short4 o;
        o.x = f2bf(v.x); o.y = f2bf(v.y); o.z = f2bf(v.z); o.w = f2bf(v.w);
        reinterpret_cast<short4*>(d)[i] = o;
    }
}

// ---------------- LayerNorm: one block per row, shuffle reduce (2 barriers) ----------------
__global__ __launch_bounds__(256)
void ln_kernel(const float* __restrict__ x, const float* __restrict__ g,
               const float* __restrict__ b, __hip_bfloat16* __restrict__ out) {
    int row = blockIdx.x;
    int t = threadIdx.x;
    const float* xr = x + (size_t)row * D_;
    float v0 = xr[t], v1 = xr[t + 256];
    __shared__ float ws4[4], qs4[4];
    float s = v0 + v1;
    #pragma unroll
    for (int o = 32; o > 0; o >>= 1) s += __shfl_down(s, o);
    if ((t & 63) == 0) ws4[t >> 6] = s;
    __syncthreads();
    float m = (ws4[0] + ws4[1] + ws4[2] + ws4[3]) * (1.0f / (float)D_);
    float d0 = v0 - m, d1 = v1 - m;
    float q = d0 * d0 + d1 * d1;
    #pragma unroll
    for (int o = 32; o > 0; o >>= 1) q += __shfl_down(q, o);
    if ((t & 63) == 0) qs4[t >> 6] = q;
    __syncthreads();
    float rs = rsqrtf((qs4[0] + qs4[1] + qs4[2] + qs4[3]) * (1.0f / (float)D_) + EPS_);
    __hip_bfloat16* orow = out + (size_t)row * D_;
    orow[t]       = __float2bfloat16(d0 * rs * g[t]       + b[t]);
    orow[t + 256] = __float2bfloat16(d1 * rs * g[t + 256] + b[t + 256]);
}

// ---------------- bf16 MFMA GEMM: C[M,N] = A[M,K] @ W[N,K]^T (+bias)(+relu)(+res) -----------
// OUT_MODE: 0 = fp32 row-major, 1 = bf16 row-major,
//           2 = fp32 xg5 layout [s][half][gate][unit64][slot8]  (half=b>>3, slot=b&7)
template<int WITH_BIAS, int WITH_RELU, int WITH_RES, int OUT_MODE>
__global__ __launch_bounds__(256)
void mfma_gemm(const __hip_bfloat16* __restrict__ A, const __hip_bfloat16* __restrict__ W,
               const float* __restrict__ bias, const float* __restrict__ res,
               void* __restrict__ C, int M, int N, int K) {
    const int LDT = 72;  // LDS row stride in shorts (144B rows, 16B-aligned)
    __shared__ short As[64 * LDT];
    __shared__ short Ws[64 * LDT];

    int tid  = threadIdx.x;
    int wave = tid >> 6, lane = tid & 63;
    int quad = lane >> 4, l16 = lane & 15;
    int m_off = (wave >> 1) * 32, n_off = (wave & 1) * 32;
    int m0 = blockIdx.y * 64, n0 = blockIdx.x * 64;

    int r = tid >> 2, c = tid & 3;           // staging: row 0..63, 16-elem chunk 0..3
    const short* Ag = reinterpret_cast<const short*>(A);
    const short* Wg = reinterpret_cast<const short*>(W);

    f32x4 acc00 = {0.f,0.f,0.f,0.f}, acc01 = acc00, acc10 = acc00, acc11 = acc00;

    short8 avA[2], avW[2];                   // staged tile in registers
    auto load_tile = [&](int k0) {
        const short* arow = &Ag[(size_t)(m0 + r) * K + k0 + c * 16];
        avA[0] = *reinterpret_cast<const short8*>(arow);
        avA[1] = *reinterpret_cast<const short8*>(arow + 8);
        const short* wrow = &Wg[(size_t)(n0 + r) * K + k0 + c * 16];
        avW[0] = *reinterpret_cast<const short8*>(wrow);
        avW[1] = *reinterpret_cast<const short8*>(wrow + 8);
    };

    load_tile(0);                            // prologue
    for (int k0 = 0; k0 < K; k0 += 64) {
        lds_barrier();                       // prev frag reads done; vmem stays in flight
        *reinterpret_cast<short8*>(&As[r * LDT + c * 16])     = avA[0];
        *reinterpret_cast<short8*>(&As[r * LDT + c * 16 + 8]) = avA[1];
        *reinterpret_cast<short8*>(&Ws[r * LDT + c * 16])     = avW[0];
        *reinterpret_cast<short8*>(&Ws[r * LDT + c * 16 + 8]) = avW[1];
        lds_barrier();
        if (k0 + 64 < K) load_tile(k0 + 64); // issue next loads; consumed next iteration

        #pragma unroll
        for (int kc = 0; kc < 2; kc++) {
            short8 a0 = *reinterpret_cast<const short8*>(&As[(m_off + l16) * LDT + kc * 32 + quad * 8]);
            short8 a1 = *reinterpret_cast<const short8*>(&As[(m_off + 16 + l16) * LDT + kc * 32 + quad * 8]);
            short8 b0 = *reinterpret_cast<const short8*>(&Ws[(n_off + l16) * LDT + kc * 32 + quad * 8]);
            short8 b1 = *reinterpret_cast<const short8*>(&Ws[(n_off + 16 + l16) * LDT + kc * 32 + quad * 8]);
            acc00 = __builtin_amdgcn_mfma_f32_16x16x32_bf16(a0, b0, acc00, 0, 0, 0);
            acc01 = __builtin_amdgcn_mfma_f32_16x16x32_bf16(a0, b1, acc01, 0, 0, 0);
            acc10 = __builtin_amdgcn_mfma_f32_16x16x32_bf16(a1, b0, acc10, 0, 0, 0);
            acc11 = __builtin_amdgcn_mfma_f32_16x16x32_bf16(a1, b1, acc11, 0, 0, 0);
        }
    }

    f32x4 accs[2][2] = {{acc00, acc01}, {acc10, acc11}};
    #pragma unroll
    for (int fi = 0; fi < 2; fi++) {
        #pragma unroll
        for (int fj = 0; fj < 2; fj++) {
            int coln = n0 + n_off + fj * 16 + l16;
            float bv = WITH_BIAS ? bias[coln] : 0.0f;
            #pragma unroll
            for (int rr = 0; rr < 4; rr++) {
                int rowm = m0 + m_off + fi * 16 + quad * 4 + rr;
                float v = accs[fi][fj][rr];
                if (WITH_BIAS) v += bv;
                if (WITH_RELU) v = fmaxf(v, 0.0f);
                if (WITH_RES)  v += res[(size_t)rowm * N + coln];
                if (OUT_MODE == 0) {
                    reinterpret_cast<float*>(C)[(size_t)rowm * N + coln] = v;
                } else if (OUT_MODE == 1) {
                    reinterpret_cast<__hip_bfloat16*>(C)[(size_t)rowm * N + coln] = __float2bfloat16(v);
                } else {
                    int b_ = rowm / S_;
                    int s_ = rowm - b_ * S_;
                    int gate = coln >> 6, u = coln & 63;
                    int half = b_ >> 3, slot = b_ & 7;
                    reinterpret_cast<float*>(C)[
                        ((((size_t)(s_ * 2 + half) * 4 + gate) * 64 + u) << 3) + slot] = v;
                }
            }
        }
    }
}

// ---------------- MFMA LSTM v10: v4 structure + shortened dependency chain ----------------
// v4/v6/v8/v9 established the step is a FIXED ~1650cy latency chain (insensitive to
// issue count / occupancy). v10 keeps v4's verified layout (grid (80,2), 4 waves,
// 2 states/lane) and shortens the chain: (1) the two K-half MFMAs per gate are
// UNCHAINED (p = mfma(af0,B0,0), q = mfma(af1,B1,0), summed in VALU) - removes one
// MFMA dep-latency from the critical path; (2) xg is added AFTER the MFMAs (folded
// into the 2-state readout) so the vmem wait sits post-MFMA; (3) xg is register-
// prefetched 2 steps deep (xvA/xvB), giving loads ~1.5 steps of flight.
__global__ __launch_bounds__(256)
void lstm_v10_kernel(const float* __restrict__ xg5,  // [S][2][4][64][8] fp32
                     const float* __restrict__ whh,  // [4H, H] fp32 (layer slice)
                     __hip_bfloat16* __restrict__ hlast) {  // [B, S, H]
    const int i    = blockIdx.x;      // output position 0..79
    const int bh   = blockIdx.y;      // batch half 0..1
    const int tid  = threadIdx.x;
    const int wave = tid >> 6, lane = tid & 63;
    const int quad = lane >> 4, l16 = lane & 15;
    const int unit = wave * 16 + l16; // hidden unit owned on the C side

    // Whh B-fragments (bf16), one-time. Tile g: col n = l16 <-> whh row g*64 + unit.
    short8 bfrag[4][2];
    #pragma unroll
    for (int g = 0; g < 4; g++) {
        const float* wr = &whh[(size_t)(g * 64 + unit) * H_];
        #pragma unroll
        for (int kc = 0; kc < 2; kc++) {
            float4 x0 = *(const float4*)(wr + kc * 32 + quad * 8);
            float4 x1 = *(const float4*)(wr + kc * 32 + quad * 8 + 4);
            short8 v;
            v[0] = f2bf(x0.x); v[1] = f2bf(x0.y); v[2] = f2bf(x0.z); v[3] = f2bf(x0.w);
            v[4] = f2bf(x1.x); v[5] = f2bf(x1.y); v[6] = f2bf(x1.z); v[7] = f2bf(x1.w);
            bfrag[g][kc] = v;
        }
    }

    // h in LDS, double-buffered by step parity; 72-short rows (144B, 16B-aligned)
    __shared__ __attribute__((aligned(16))) short hsh[2][16][72];
    for (int idx = tid; idx < 2 * 16 * 72; idx += 256)
        reinterpret_cast<short*>(hsh)[idx] = 0;

    float cst[2] = {0.f, 0.f};
    float hvv[2] = {0.f, 0.f};

    // xg float2 addresses: (((s*2+bh)*4 + g)*64 + unit)*8 + quad*2
    size_t xoff[4];
    #pragma unroll
    for (int g = 0; g < 4; g++)
        xoff[g] = ((((size_t)bh * 4 + g) * 64 + unit) << 3) + quad * 2;

    auto xload = [&](float2 (&xv)[4], int t) {
        int s = (t == i) ? (S_ - 1) : ((t == S_ - 1) ? i : t);   // janossy permutation
        const float* base = xg5 + (size_t)s * 4096;
        #pragma unroll
        for (int g = 0; g < 4; g++)
            xv[g] = *reinterpret_cast<const float2*>(base + xoff[g]);
    };

    float2 xvA[4], xvB[4];
    xload(xvA, 0);
    xload(xvB, 1);

    lds_barrier();  // LDS zero-init visible

    const f32x4 zacc = {0.f, 0.f, 0.f, 0.f};

    auto stepv = [&](int t, float2 (&xc)[4]) {
        const int pb = t & 1;
        short8 af0 = *reinterpret_cast<const short8*>(&hsh[pb][l16][quad * 8]);
        short8 af1 = *reinterpret_cast<const short8*>(&hsh[pb][l16][32 + quad * 8]);

        // unchained MFMA pairs: p (K 0..31) and q (K 32..63) independent, summed in VALU
        f32x4 p0 = __builtin_amdgcn_mfma_f32_16x16x32_bf16(af0, bfrag[0][0], zacc, 0, 0, 0);
        f32x4 q0 = __builtin_amdgcn_mfma_f32_16x16x32_bf16(af1, bfrag[0][1], zacc, 0, 0, 0);
        f32x4 p1 = __builtin_amdgcn_mfma_f32_16x16x32_bf16(af0, bfrag[1][0], zacc, 0, 0, 0);
        f32x4 q1 = __builtin_amdgcn_mfma_f32_16x16x32_bf16(af1, bfrag[1][1], zacc, 0, 0, 0);
        f32x4 p2 = __builtin_amdgcn_mfma_f32_16x16x32_bf16(af0, bfrag[2][0], zacc, 0, 0, 0);
        f32x4 q2 = __builtin_amdgcn_mfma_f32_16x16x32_bf16(af1, bfrag[2][1], zacc, 0, 0, 0);
        f32x4 p3 = __builtin_amdgcn_mfma_f32_16x16x32_bf16(af0, bfrag[3][0], zacc, 0, 0, 0);
        f32x4 q3 = __builtin_amdgcn_mfma_f32_16x16x32_bf16(af1, bfrag[3][1], zacc, 0, 0, 0);

        // gate sums: xg added here (post-MFMA), rows 0,1 only
        float gi0 = p0[0] + q0[0] + xc[0].x, gi1 = p0[1] + q0[1] + xc[0].y;
        float gf0 = p1[0] + q1[0] + xc[1].x, gf1 = p1[1] + q1[1] + xc[1].y;
        float gg0 = p2[0] + q2[0] + xc[2].x, gg1 = p2[1] + q2[1] + xc[2].y;
        float go0 = p3[0] + q3[0] + xc[3].x, go1 = p3[1] + q3[1] + xc[3].y;

        // prefetch xg for t+2 into the buffer just consumed (~1.5 steps in flight)
        if (t + 2 < S_) xload(xc, t + 2);

        {   // state 0 (batch quad*2+0)
            float ig = sigmoidf_(gi0);
            float fg = sigmoidf_(gf0);
            float gv = tanh_(gg0);
            float og = sigmoidf_(go0);
            float cc = fg * cst[0] + ig * gv;
            cst[0] = cc;
            float h = og * tanh_(cc);
            hvv[0] = h;
            hsh[pb ^ 1][quad * 4 + 0][unit] = f2bf(h);
        }
        {   // state 1 (batch quad*2+1)
            float ig = sigmoidf_(gi1);
            float fg = sigmoidf_(gf1);
            float gv = tanh_(gg1);
            float og = sigmoidf_(go1);
            float cc = fg * cst[1] + ig * gv;
            cst[1] = cc;
            float h = og * tanh_(cc);
            hvv[1] = h;
            hsh[pb ^ 1][quad * 4 + 1][unit] = f2bf(h);
        }
        lds_barrier();
    };

    for (int t = 0; t < S_; t += 2) { stepv(t, xvA); stepv(t + 1, xvB); }

    #pragma unroll
    for (int r = 0; r < 2; r++) {
        int b = bh * 8 + quad * 2 + r;
        hlast[((size_t)b * S_ + i) * H_ + unit] = __float2bfloat16(hvv[r]);
    }
}

// ---------------- final LN + projection to one logit per row ----------------
__global__ __launch_bounds__(256)
void final_kernel(const float* __restrict__ x, const float* __restrict__ g,
                  const float* __restrict__ b, const float* __restrict__ wprj,
                  float* __restrict__ out) {
    int row = blockIdx.x;
    int t = threadIdx.x;
    const float* xr = x + (size_t)row * D_;
    float v0 = xr[t], v1 = xr[t + 256];
    __shared__ float red[256];
    red[t] = v0 + v1;
    __syncthreads();
    for (int o = 128; o > 0; o >>= 1) { if (t < o) red[t] += red[t + o]; __syncthreads(); }
    float m = red[0] * (1.0f / (float)D_);
    __syncthreads();
    float d0 = v0 - m, d1 = v1 - m;
    red[t] = d0 * d0 + d1 * d1;
    __syncthreads();
    for (int o = 128; o > 0; o >>= 1) { if (t < o) red[t] += red[t + o]; __syncthreads(); }
    float rs = rsqrtf(red[0] * (1.0f / (float)D_) + EPS_);
    __syncthreads();
    float y0 = (d0 * rs * g[t] + b[t]) * wprj[t];
    float y1 = (d1 * rs * g[t + 256] + b[t + 256]) * wprj[t + 256];
    red[t] = y0 + y1;
    __syncthreads();
    for (int o = 128; o > 0; o >>= 1) { if (t < o) red[t] += red[t + o]; __syncthreads(); }
    if (t == 0) out[row] = red[0];
}

// ---------------- host ----------------
extern "C" void kernel_launch(void* const* d_in, const int* in_sizes, int n_in,
                              void* d_out, int out_size, void* d_ws, size_t ws_size,
                              hipStream_t stream) {
    const float* src   = (const float*)d_in[0];
    const float* ln1_g = (const float*)d_in[2];
    const float* ln1_b = (const float*)d_in[3];
    const float* wih   = (const float*)d_in[4];   // [L, 4H, D]
    const float* whh   = (const float*)d_in[5];   // [L, 4H, H]
    const float* wfc   = (const float*)d_in[6];   // [L, D, H]
    const float* ln2_g = (const float*)d_in[7];
    const float* ln2_b = (const float*)d_in[8];
    const float* w1    = (const float*)d_in[9];   // [L, DI, D]
    const float* b1    = (const float*)d_in[10];  // [L, DI]
    const float* w2    = (const float*)d_in[11];  // [L, D, DI]
    const float* b2    = (const float*)d_in[12];  // [L, D]
    const float* lnf_g = (const float*)d_in[13];
    const float* lnf_b = (const float*)d_in[14];
    const float* wprj  = (const float*)d_in[15];  // [1, D]
    float* out = (float*)d_out;

    char* ws = (char*)d_ws;
    float* xcur = (float*)ws;                       ws += (size_t)NROW * D_  * 4;  // fp32 residual stream
    __hip_bfloat16* lnb = (__hip_bfloat16*)ws;      ws += (size_t)NROW * D_  * 2;  // LN output (bf16 A-operand)
    float* xg5  = (float*)ws;                       ws += (size_t)S_ * 4096  * 4;  // gate proj fp32 [s][2][4][64][8]
    __hip_bfloat16* hb  = (__hip_bfloat16*)ws;      ws += (size_t)NROW * H_  * 2;  // LSTM h (bf16 A-operand)
    __hip_bfloat16* f1  = (__hip_bfloat16*)ws;      ws += (size_t)NROW * DI_ * 2;  // FFN hidden (bf16 A-operand)
    __hip_bfloat16* wihb = (__hip_bfloat16*)ws;     ws += (size_t)L_ * G4H * D_ * 2;
    __hip_bfloat16* wfcb = (__hip_bfloat16*)ws;     ws += (size_t)L_ * D_ * H_ * 2;
    __hip_bfloat16* w1b  = (__hip_bfloat16*)ws;     ws += (size_t)L_ * DI_ * D_ * 2;
    __hip_bfloat16* w2b  = (__hip_bfloat16*)ws;     ws += (size_t)L_ * D_ * DI_ * 2;

    // one-time (per launch) weight conversions to bf16
    {
        int n4;
        n4 = L_ * G4H * D_ / 4;
        w2bf_kernel<<<(n4 + 255) / 256, 256, 0, stream>>>(wih, wihb, n4);
        n4 = L_ * D_ * H_ / 4;
        w2bf_kernel<<<(n4 + 255) / 256, 256, 0, stream>>>(wfc, wfcb, n4);
        n4 = L_ * DI_ * D_ / 4;
        w2bf_kernel<<<(n4 + 255) / 256, 256, 0, stream>>>(w1, w1b, n4);
        n4 = L_ * D_ * DI_ / 4;
        w2bf_kernel<<<(n4 + 255) / 256, 256, 0, stream>>>(w2, w2b, n4);
    }

    hipMemcpyAsync(xcur, src, (size_t)NROW * D_ * sizeof(float),
                   hipMemcpyDeviceToDevice, stream);

    for (int l = 0; l < L_; l++) {
        // --- janossy layer ---
        ln_kernel<<<NROW, 256, 0, stream>>>(xcur, ln1_g + (size_t)l * D_,
                                            ln1_b + (size_t)l * D_, lnb);
        mfma_gemm<0, 0, 0, 2><<<dim3(G4H / 64, NROW / 64), 256, 0, stream>>>(
            lnb, wihb + (size_t)l * G4H * D_, nullptr, nullptr, xg5, NROW, G4H, D_);
        lstm_v10_kernel<<<dim3(S_, 2), 256, 0, stream>>>(
            xg5, whh + (size_t)l * G4H * H_, hb);
        mfma_gemm<0, 0, 1, 0><<<dim3(D_ / 64, NROW / 64), 256, 0, stream>>>(
            hb, wfcb + (size_t)l * D_ * H_, nullptr, xcur, xcur, NROW, D_, H_);
        // --- FFN ---
        ln_kernel<<<NROW, 256, 0, stream>>>(xcur, ln2_g + (size_t)l * D_,
                                            ln2_b + (size_t)l * D_, lnb);
        mfma_gemm<1, 1, 0, 1><<<dim3(DI_ / 64, NROW / 64), 256, 0, stream>>>(
            lnb, w1b + (size_t)l * DI_ * D_, b1 + (size_t)l * DI_, nullptr, f1, NROW, DI_, D_);
        mfma_gemm<1, 0, 1, 0><<<dim3(D_ / 64, NROW / 64), 256, 0, stream>>>(
            f1, w2b + (size_t)l * D_ * DI_, b2 + (size_t)l * D_, xcur, xcur, NROW, D_, DI_);
    }
    final_kernel<<<NROW, 256, 0, stream>>>(xcur, lnf_g, lnf_b, wprj, out);
}